// Round 1
// baseline (78002.252 us; speedup 1.0000x reference)
//
#include <hip/hip_runtime.h>
#include <math.h>

#define TT 1500
#define BB 16
#define HH 1024
#define MM (TT*BB)            // 24000
#define KEEPF 0.8f
#define EPSF 1e-5f
#define NFLT ((size_t)MM * HH)   // 24,576,000 floats per [T,B,H] buffer

#define AGENT __HIP_MEMORY_SCOPE_AGENT

// ---------------- two-level grid barrier (256 blocks = 8 groups x 32) ----------------
__device__ __forceinline__ void gsync(unsigned* bar) {
    __syncthreads();
    if (threadIdx.x == 0) {
        unsigned* gen  = bar + 288;
        unsigned* root = bar + 256;
        unsigned g = __hip_atomic_load(gen, __ATOMIC_RELAXED, AGENT);
        unsigned* gc = bar + ((blockIdx.x >> 5) << 5);   // 128B-spaced group counters
        unsigned a = __hip_atomic_fetch_add(gc, 1u, __ATOMIC_ACQ_REL, AGENT);
        if (a == 31u) {
            __hip_atomic_store(gc, 0u, __ATOMIC_RELAXED, AGENT);
            unsigned r = __hip_atomic_fetch_add(root, 1u, __ATOMIC_ACQ_REL, AGENT);
            if (r == 7u) {
                __hip_atomic_store(root, 0u, __ATOMIC_RELAXED, AGENT);
                __hip_atomic_store(gen, g + 1u, __ATOMIC_RELEASE, AGENT);
            } else {
                while (__hip_atomic_load(gen, __ATOMIC_ACQUIRE, AGENT) == g)
                    __builtin_amdgcn_s_sleep(1);
            }
        } else {
            while (__hip_atomic_load(gen, __ATOMIC_ACQUIRE, AGENT) == g)
                __builtin_amdgcn_s_sleep(1);
        }
    }
    __syncthreads();
}

// ---------------- GEMM + folded BatchNorm ----------------
// out[m, j] = BN( sum_k A[m,k] * W[j,k] ),  combined N=2048: j<1024 -> (Wh, bnh, outh), else (Wz, bnz, outz)
__global__ __launch_bounds__(256) void gemm_bn_kernel(
    const float* __restrict__ A, int K,
    const float* __restrict__ Wh, const float* __restrict__ Wz,
    const float* __restrict__ bnh_g, const float* __restrict__ bnh_b,
    const float* __restrict__ bnh_m, const float* __restrict__ bnh_v,
    const float* __restrict__ bnz_g, const float* __restrict__ bnz_b,
    const float* __restrict__ bnz_m, const float* __restrict__ bnz_v,
    float* __restrict__ outh, float* __restrict__ outz)
{
    __shared__ float As[16][68];
    __shared__ float Ws[16][68];
    const int mb = blockIdx.x;          // 0..374  (64 rows each)
    const int nb = blockIdx.y;          // 0..31   (64 combined cols each)
    const int jbase = nb * 64;
    const bool isz = jbase >= 1024;
    const float* W = isz ? Wz : Wh;
    const int jloc = isz ? (jbase - 1024) : jbase;   // column base within its half

    const int tid = threadIdx.x;
    const int r = tid >> 2, q = tid & 3;
    const int tm = tid & 15, tn = tid >> 4;

    float acc[4][4] = {};
    for (int kt = 0; kt < K; kt += 16) {
        float4 a = *(const float4*)(A + (size_t)(mb * 64 + r) * K + kt + q * 4);
        float4 w = *(const float4*)(W + (size_t)(jloc + r) * K + kt + q * 4);
        __syncthreads();
        As[q*4+0][r] = a.x; As[q*4+1][r] = a.y; As[q*4+2][r] = a.z; As[q*4+3][r] = a.w;
        Ws[q*4+0][r] = w.x; Ws[q*4+1][r] = w.y; Ws[q*4+2][r] = w.z; Ws[q*4+3][r] = w.w;
        __syncthreads();
        #pragma unroll
        for (int k = 0; k < 16; ++k) {
            float4 a4 = *(const float4*)(&As[k][tm * 4]);
            float4 w4 = *(const float4*)(&Ws[k][tn * 4]);
            float av[4] = {a4.x, a4.y, a4.z, a4.w};
            float wv[4] = {w4.x, w4.y, w4.z, w4.w};
            #pragma unroll
            for (int i = 0; i < 4; ++i)
                #pragma unroll
                for (int j = 0; j < 4; ++j)
                    acc[i][j] += av[i] * wv[j];
        }
    }

    const float* g = isz ? bnz_g : bnh_g;
    const float* b = isz ? bnz_b : bnh_b;
    const float* m = isz ? bnz_m : bnh_m;
    const float* v = isz ? bnz_v : bnh_v;
    float* outp = isz ? outz : outh;

    float sc[4], sh[4];
    #pragma unroll
    for (int j = 0; j < 4; ++j) {
        int jc = jloc + tn * 4 + j;
        float s = g[jc] * rsqrtf(v[jc] + EPSF);
        sc[j] = s;
        sh[j] = b[jc] - m[jc] * s;
    }
    #pragma unroll
    for (int i = 0; i < 4; ++i) {
        int mrow = mb * 64 + tm * 4 + i;
        float4 o;
        o.x = acc[i][0] * sc[0] + sh[0];
        o.y = acc[i][1] * sc[1] + sh[1];
        o.z = acc[i][2] * sc[2] + sh[2];
        o.w = acc[i][3] * sc[3] + sh[3];
        *(float4*)(outp + (size_t)mrow * HH + jloc + tn * 4) = o;
    }
}

// ---------------- persistent cooperative liGRU scan ----------------
// 256 blocks x 256 threads; block owns columns [bid*4, bid*4+4).
// thread: tile = tid>>4 (mat|bq|jq bits), ks = tid&15 (interleaved k-slices)
__global__ __launch_bounds__(256) void scan_kernel(
    const float* __restrict__ wh, const float* __restrict__ wz,
    const float* __restrict__ uh, const float* __restrict__ uz,
    float* __restrict__ hout, unsigned* bar)
{
    __shared__ float hs[BB][HH];   // 64 KB, full h state
    const int tid = threadIdx.x, bid = blockIdx.x;
    float4* hs4 = (float4*)hs;
    #pragma unroll
    for (int i = 0; i < 16; ++i) hs4[i * 256 + tid] = make_float4(0.f, 0.f, 0.f, 0.f);
    __syncthreads();

    const int tile = tid >> 4, ks = tid & 15;
    const int mat = tile & 1, bq = (tile >> 1) & 3, jq = (tile >> 3) & 1;
    const int j0 = bid * 4 + jq * 2;
    const float* U = mat ? uz : uh;
    const float* u0 = U + (size_t)j0 * HH;
    const float* u1 = u0 + HH;

    for (int t = 0; t < TT; ++t) {
        float acc0[4] = {0.f, 0.f, 0.f, 0.f};
        float acc1[4] = {0.f, 0.f, 0.f, 0.f};
        #pragma unroll
        for (int it = 0; it < 16; ++it) {
            const int k = it * 64 + ks * 4;      // interleaved: lanes read contiguous 256B
            float4 ua = *(const float4*)(u0 + k);
            float4 ub = *(const float4*)(u1 + k);
            #pragma unroll
            for (int bi = 0; bi < 4; ++bi) {
                float4 hv = *(const float4*)(&hs[bq * 4 + bi][k]);
                acc0[bi] += hv.x * ua.x + hv.y * ua.y + hv.z * ua.z + hv.w * ua.w;
                acc1[bi] += hv.x * ub.x + hv.y * ub.y + hv.z * ub.z + hv.w * ub.w;
            }
        }
        // reduce over the 16 k-slices (butterfly -> all 16 lanes hold the sum)
        #pragma unroll
        for (int d = 1; d < 16; d <<= 1) {
            #pragma unroll
            for (int bi = 0; bi < 4; ++bi) {
                acc0[bi] += __shfl_xor(acc0[bi], d, 64);
                acc1[bi] += __shfl_xor(acc1[bi], d, 64);
            }
        }
        // exchange with the partner mat group (lane ^ 16)
        float z0[4], z1[4];
        #pragma unroll
        for (int bi = 0; bi < 4; ++bi) {
            z0[bi] = __shfl_xor(acc0[bi], 16, 64);
            z1[bi] = __shfl_xor(acc1[bi], 16, 64);
        }
        if (mat == 0 && ks == 0) {   // 8 update lanes per block, each handles 2j x 4b
            #pragma unroll
            for (int jj = 0; jj < 2; ++jj) {
                const int j = j0 + jj;
                #pragma unroll
                for (int bi = 0; bi < 4; ++bi) {
                    const int b = bq * 4 + bi;
                    const size_t idx = ((size_t)t * BB + b) * HH + j;
                    const float adot = jj ? acc1[bi] : acc0[bi];
                    const float zdot = jj ? z1[bi] : z0[bi];
                    const float a  = wh[idx] + adot;
                    const float zp = wz[idx] + zdot;
                    const float zt = 1.f / (1.f + expf(-zp));
                    const float hc = fmaxf(a, 0.f) * KEEPF;
                    const float hn = zt * hs[b][j] + (1.f - zt) * hc;
                    hout[idx] = hn;
                }
            }
        }
        gsync(bar);
        // broadcast: reload full h[t] into LDS
        const float4* src = (const float4*)(hout + (size_t)t * BB * HH);
        #pragma unroll
        for (int i = 0; i < 16; ++i) hs4[i * 256 + tid] = src[i * 256 + tid];
        __syncthreads();
    }
}

__global__ void lencopy_kernel(const int* __restrict__ xl, float* __restrict__ out) {
    int i = threadIdx.x;
    if (i < BB) out[i] = (float)xl[i];
}

extern "C" void kernel_launch(void* const* d_in, const int* in_sizes, int n_in,
                              void* d_out, int out_size, void* d_ws, size_t ws_size,
                              hipStream_t stream) {
    const float* x    = (const float*)d_in[0];
    const int*   xlen = (const int*)d_in[1];
    const float* whW0 = (const float*)d_in[2];
    const float* wzW0 = (const float*)d_in[3];
    const float* uhW0 = (const float*)d_in[4];
    const float* uzW0 = (const float*)d_in[5];
    const float* bnh0[4] = {(const float*)d_in[6], (const float*)d_in[7], (const float*)d_in[8], (const float*)d_in[9]};
    const float* bnz0[4] = {(const float*)d_in[10], (const float*)d_in[11], (const float*)d_in[12], (const float*)d_in[13]};
    const float* whW1 = (const float*)d_in[14];
    const float* wzW1 = (const float*)d_in[15];
    const float* uhW1 = (const float*)d_in[16];
    const float* uzW1 = (const float*)d_in[17];
    const float* bnh1[4] = {(const float*)d_in[18], (const float*)d_in[19], (const float*)d_in[20], (const float*)d_in[21]};
    const float* bnz1[4] = {(const float*)d_in[22], (const float*)d_in[23], (const float*)d_in[24], (const float*)d_in[25]};

    float* whb = (float*)d_ws;               // [M,H]
    float* wzb = whb + NFLT;                 // [M,H]
    float* h0  = wzb + NFLT;                 // [M,H]
    unsigned* bar = (unsigned*)((char*)d_ws + 3 * NFLT * sizeof(float));
    float* out0 = (float*)d_out;             // h1 [T,B,H]

    // barrier area must be zero every launch (ws is re-poisoned)
    hipMemsetAsync(bar, 0, 4096, stream);

    dim3 ggrid(MM / 64, 32), gblk(256);

    // layer 0 projections + BN
    gemm_bn_kernel<<<ggrid, gblk, 0, stream>>>(
        x, 512, whW0, wzW0,
        bnh0[0], bnh0[1], bnh0[2], bnh0[3],
        bnz0[0], bnz0[1], bnz0[2], bnz0[3],
        whb, wzb);

    // layer 0 scan
    {
        const float* a0 = whb; const float* a1 = wzb;
        const float* a2 = uhW0; const float* a3 = uzW0;
        float* a4 = h0; unsigned* a5 = bar;
        void* args[] = {&a0, &a1, &a2, &a3, &a4, &a5};
        hipLaunchCooperativeKernel((const void*)scan_kernel, dim3(256), dim3(256), args, 0, stream);
    }

    // layer 1 projections + BN (reuse wh/wz buffers)
    gemm_bn_kernel<<<ggrid, gblk, 0, stream>>>(
        h0, 1024, whW1, wzW1,
        bnh1[0], bnh1[1], bnh1[2], bnh1[3],
        bnz1[0], bnz1[1], bnz1[2], bnz1[3],
        whb, wzb);

    // layer 1 scan -> d_out
    {
        const float* a0 = whb; const float* a1 = wzb;
        const float* a2 = uhW1; const float* a3 = uzW1;
        float* a4 = out0; unsigned* a5 = bar;
        void* args[] = {&a0, &a1, &a2, &a3, &a4, &a5};
        hipLaunchCooperativeKernel((const void*)scan_kernel, dim3(256), dim3(256), args, 0, stream);
    }

    // x_len pass-through as float values
    lencopy_kernel<<<1, 64, 0, stream>>>(xlen, out0 + NFLT);
}

// Round 2
// 42195.792 us; speedup vs baseline: 1.8486x; 1.8486x over previous
//
#include <hip/hip_runtime.h>
#include <math.h>

#define TT 1500
#define BB 16
#define HH 1024
#define MM (TT*BB)            // 24000
#define KEEPF 0.8f
#define EPSF 1e-5f
#define NFLT ((size_t)MM * HH)   // 24,576,000 floats per [T,B,H] buffer

#define AGENT __HIP_MEMORY_SCOPE_AGENT

// ---------------- monotonic two-level grid barrier (256 blocks = 8 groups x 32) ----
// All RELAXED atomics: data is transported via coherent (L2-bypassing) atomic
// ops, so no acquire/release cache maintenance (buffer_inv / buffer_wbl2) is
// needed. Counters are monotonic (epoch-indexed targets) -> no reset races.
__device__ __forceinline__ void gsync(unsigned* bar, int t) {
    __syncthreads();   // drains vmcnt: this block's coherent h-stores are at L3
    if (threadIdx.x == 0) {
        unsigned* gen  = bar + 288;
        unsigned* root = bar + 256;
        unsigned* gc   = bar + ((blockIdx.x >> 5) << 5);   // 128B-spaced group counters
        const unsigned want = (unsigned)(t + 1);
        unsigned a = __hip_atomic_fetch_add(gc, 1u, __ATOMIC_RELAXED, AGENT);
        if (a == (unsigned)t * 32u + 31u) {
            unsigned r = __hip_atomic_fetch_add(root, 1u, __ATOMIC_RELAXED, AGENT);
            if (r == (unsigned)t * 8u + 7u) {
                __hip_atomic_store(gen, want, __ATOMIC_RELAXED, AGENT);
            } else {
                while (__hip_atomic_load(gen, __ATOMIC_RELAXED, AGENT) < want)
                    __builtin_amdgcn_s_sleep(1);
            }
        } else {
            while (__hip_atomic_load(gen, __ATOMIC_RELAXED, AGENT) < want)
                __builtin_amdgcn_s_sleep(1);
        }
        asm volatile("" ::: "memory");
    }
    __syncthreads();
}

// ---------------- GEMM + folded BatchNorm (unchanged from round 1) ----------------
__global__ __launch_bounds__(256) void gemm_bn_kernel(
    const float* __restrict__ A, int K,
    const float* __restrict__ Wh, const float* __restrict__ Wz,
    const float* __restrict__ bnh_g, const float* __restrict__ bnh_b,
    const float* __restrict__ bnh_m, const float* __restrict__ bnh_v,
    const float* __restrict__ bnz_g, const float* __restrict__ bnz_b,
    const float* __restrict__ bnz_m, const float* __restrict__ bnz_v,
    float* __restrict__ outh, float* __restrict__ outz)
{
    __shared__ float As[16][68];
    __shared__ float Ws[16][68];
    const int mb = blockIdx.x;
    const int nb = blockIdx.y;
    const int jbase = nb * 64;
    const bool isz = jbase >= 1024;
    const float* W = isz ? Wz : Wh;
    const int jloc = isz ? (jbase - 1024) : jbase;

    const int tid = threadIdx.x;
    const int r = tid >> 2, q = tid & 3;
    const int tm = tid & 15, tn = tid >> 4;

    float acc[4][4] = {};
    for (int kt = 0; kt < K; kt += 16) {
        float4 a = *(const float4*)(A + (size_t)(mb * 64 + r) * K + kt + q * 4);
        float4 w = *(const float4*)(W + (size_t)(jloc + r) * K + kt + q * 4);
        __syncthreads();
        As[q*4+0][r] = a.x; As[q*4+1][r] = a.y; As[q*4+2][r] = a.z; As[q*4+3][r] = a.w;
        Ws[q*4+0][r] = w.x; Ws[q*4+1][r] = w.y; Ws[q*4+2][r] = w.z; Ws[q*4+3][r] = w.w;
        __syncthreads();
        #pragma unroll
        for (int k = 0; k < 16; ++k) {
            float4 a4 = *(const float4*)(&As[k][tm * 4]);
            float4 w4 = *(const float4*)(&Ws[k][tn * 4]);
            float av[4] = {a4.x, a4.y, a4.z, a4.w};
            float wv[4] = {w4.x, w4.y, w4.z, w4.w};
            #pragma unroll
            for (int i = 0; i < 4; ++i)
                #pragma unroll
                for (int j = 0; j < 4; ++j)
                    acc[i][j] += av[i] * wv[j];
        }
    }

    const float* g = isz ? bnz_g : bnh_g;
    const float* b = isz ? bnz_b : bnh_b;
    const float* m = isz ? bnz_m : bnh_m;
    const float* v = isz ? bnz_v : bnh_v;
    float* outp = isz ? outz : outh;

    float sc[4], sh[4];
    #pragma unroll
    for (int j = 0; j < 4; ++j) {
        int jc = jloc + tn * 4 + j;
        float s = g[jc] * rsqrtf(v[jc] + EPSF);
        sc[j] = s;
        sh[j] = b[jc] - m[jc] * s;
    }
    #pragma unroll
    for (int i = 0; i < 4; ++i) {
        int mrow = mb * 64 + tm * 4 + i;
        float4 o;
        o.x = acc[i][0] * sc[0] + sh[0];
        o.y = acc[i][1] * sc[1] + sh[1];
        o.z = acc[i][2] * sc[2] + sh[2];
        o.w = acc[i][3] * sc[3] + sh[3];
        *(float4*)(outp + (size_t)mrow * HH + jloc + tn * 4) = o;
    }
}

// ---------------- persistent cooperative liGRU scan ----------------
// 256 blocks x 256 threads; block owns columns [bid*4, bid*4+4).
// thread: ks = tid&15 (k-slice), grp = tid>>4: mat = grp&1, bq = grp>>1 (2 rows each).
// Each thread covers 4 cols x 2 rows -> LDS dot traffic 128 KB/block/step.
#define DOT4(acc, hv, uv) (acc += (hv).x*(uv).x + (hv).y*(uv).y + (hv).z*(uv).z + (hv).w*(uv).w)

__global__ __launch_bounds__(256) void scan_kernel(
    const float* __restrict__ wh, const float* __restrict__ wz,
    const float* __restrict__ uh, const float* __restrict__ uz,
    float* __restrict__ hout, unsigned* bar)
{
    __shared__ float hs[BB][HH];   // 64 KB, full h state
    const int tid = threadIdx.x, bid = blockIdx.x;
    unsigned long long* hs8 = (unsigned long long*)&hs[0][0];
    #pragma unroll
    for (int i = 0; i < 32; ++i) hs8[i * 256 + tid] = 0ull;
    __syncthreads();

    const int ks  = tid & 15;
    const int grp = tid >> 4;          // 0..15
    const int mat = grp & 1;
    const int bq  = grp >> 1;          // 0..7 -> rows 2bq, 2bq+1
    const int j0  = bid * 4;
    const float* U  = mat ? uz : uh;
    const float* u0 = U + (size_t)(j0 + 0) * HH;
    const float* u1 = U + (size_t)(j0 + 1) * HH;
    const float* u2 = U + (size_t)(j0 + 2) * HH;
    const float* u3 = U + (size_t)(j0 + 3) * HH;
    const bool upd = (mat == 0) && (ks == 0);   // 8 lanes/block

    for (int t = 0; t < TT; ++t) {
        // prefetch gate inputs early (latency hidden under the dot loop)
        float4 whv0, whv1, wzv0, wzv1;
        if (upd) {
            const size_t base = ((size_t)t * BB + bq * 2) * HH + j0;
            whv0 = *(const float4*)(wh + base);
            whv1 = *(const float4*)(wh + base + HH);
            wzv0 = *(const float4*)(wz + base);
            wzv1 = *(const float4*)(wz + base + HH);
        }

        float a0[4] = {0,0,0,0}, a1[4] = {0,0,0,0};
        #pragma unroll
        for (int it = 0; it < 16; ++it) {
            const int k = it * 64 + ks * 4;     // lanes read contiguous 256B
            float4 x0 = *(const float4*)(u0 + k);
            float4 x1 = *(const float4*)(u1 + k);
            float4 x2 = *(const float4*)(u2 + k);
            float4 x3 = *(const float4*)(u3 + k);
            float4 h0 = *(const float4*)(&hs[bq * 2 + 0][k]);
            float4 h1 = *(const float4*)(&hs[bq * 2 + 1][k]);
            DOT4(a0[0], h0, x0); DOT4(a0[1], h0, x1); DOT4(a0[2], h0, x2); DOT4(a0[3], h0, x3);
            DOT4(a1[0], h1, x0); DOT4(a1[1], h1, x1); DOT4(a1[2], h1, x2); DOT4(a1[3], h1, x3);
        }
        // butterfly reduce over the 16 k-slices
        #pragma unroll
        for (int d = 1; d < 16; d <<= 1) {
            #pragma unroll
            for (int j = 0; j < 4; ++j) {
                a0[j] += __shfl_xor(a0[j], d, 64);
                a1[j] += __shfl_xor(a1[j], d, 64);
            }
        }
        // pair with the z-matrix partner (lane ^ 16 flips mat)
        float z0[4], z1[4];
        #pragma unroll
        for (int j = 0; j < 4; ++j) {
            z0[j] = __shfl_xor(a0[j], 16, 64);
            z1[j] = __shfl_xor(a1[j], 16, 64);
        }

        if (upd) {
            #pragma unroll
            for (int r = 0; r < 2; ++r) {
                const int b = bq * 2 + r;
                const float4 whv = r ? whv1 : whv0;
                const float4 wzv = r ? wzv1 : wzv0;
                const float* ad = r ? a1 : a0;
                const float* zd = r ? z1 : z0;
                float hn[4];
                #pragma unroll
                for (int j = 0; j < 4; ++j) {
                    const float zt = 1.f / (1.f + __expf(-((&wzv.x)[j] + zd[j])));
                    const float at = (&whv.x)[j] + ad[j];
                    const float hc = fmaxf(at, 0.f) * KEEPF;
                    hn[j] = zt * hs[b][j0 + j] + (1.f - zt) * hc;
                }
                // coherent (L2-bypassing) 8B stores -> visible at L3 for all XCDs
                unsigned long long* dst = (unsigned long long*)(hout + ((size_t)t * BB + b) * HH + j0);
                union { float f[2]; unsigned long long u; } p0, p1;
                p0.f[0] = hn[0]; p0.f[1] = hn[1];
                p1.f[0] = hn[2]; p1.f[1] = hn[3];
                __hip_atomic_store(dst + 0, p0.u, __ATOMIC_RELAXED, AGENT);
                __hip_atomic_store(dst + 1, p1.u, __ATOMIC_RELAXED, AGENT);
            }
        }

        gsync(bar, t);

        // broadcast: reload full h[t] into LDS via coherent loads (no cache flush)
        const unsigned long long* src = (const unsigned long long*)(hout + (size_t)t * BB * HH);
        #pragma unroll
        for (int i = 0; i < 32; ++i)
            hs8[i * 256 + tid] = __hip_atomic_load(src + i * 256 + tid, __ATOMIC_RELAXED, AGENT);
        __syncthreads();
    }
}

__global__ void lencopy_kernel(const int* __restrict__ xl, float* __restrict__ out) {
    int i = threadIdx.x;
    if (i < BB) out[i] = (float)xl[i];
}

extern "C" void kernel_launch(void* const* d_in, const int* in_sizes, int n_in,
                              void* d_out, int out_size, void* d_ws, size_t ws_size,
                              hipStream_t stream) {
    const float* x    = (const float*)d_in[0];
    const int*   xlen = (const int*)d_in[1];
    const float* whW0 = (const float*)d_in[2];
    const float* wzW0 = (const float*)d_in[3];
    const float* uhW0 = (const float*)d_in[4];
    const float* uzW0 = (const float*)d_in[5];
    const float* bnh0[4] = {(const float*)d_in[6], (const float*)d_in[7], (const float*)d_in[8], (const float*)d_in[9]};
    const float* bnz0[4] = {(const float*)d_in[10], (const float*)d_in[11], (const float*)d_in[12], (const float*)d_in[13]};
    const float* whW1 = (const float*)d_in[14];
    const float* wzW1 = (const float*)d_in[15];
    const float* uhW1 = (const float*)d_in[16];
    const float* uzW1 = (const float*)d_in[17];
    const float* bnh1[4] = {(const float*)d_in[18], (const float*)d_in[19], (const float*)d_in[20], (const float*)d_in[21]};
    const float* bnz1[4] = {(const float*)d_in[22], (const float*)d_in[23], (const float*)d_in[24], (const float*)d_in[25]};

    float* whb = (float*)d_ws;               // [M,H]
    float* wzb = whb + NFLT;                 // [M,H]
    float* h0  = wzb + NFLT;                 // [M,H]
    unsigned* bar = (unsigned*)((char*)d_ws + 3 * NFLT * sizeof(float));
    float* out0 = (float*)d_out;             // h1 [T,B,H]

    dim3 ggrid(MM / 64, 32), gblk(256);

    // layer 0 projections + BN
    gemm_bn_kernel<<<ggrid, gblk, 0, stream>>>(
        x, 512, whW0, wzW0,
        bnh0[0], bnh0[1], bnh0[2], bnh0[3],
        bnz0[0], bnz0[1], bnz0[2], bnz0[3],
        whb, wzb);

    // layer 0 scan
    hipMemsetAsync(bar, 0, 4096, stream);
    {
        const float* a0 = whb; const float* a1 = wzb;
        const float* a2 = uhW0; const float* a3 = uzW0;
        float* a4 = h0; unsigned* a5 = bar;
        void* args[] = {&a0, &a1, &a2, &a3, &a4, &a5};
        hipLaunchCooperativeKernel((const void*)scan_kernel, dim3(256), dim3(256), args, 0, stream);
    }

    // layer 1 projections + BN (reuse wh/wz buffers)
    gemm_bn_kernel<<<ggrid, gblk, 0, stream>>>(
        h0, 1024, whW1, wzW1,
        bnh1[0], bnh1[1], bnh1[2], bnh1[3],
        bnz1[0], bnz1[1], bnz1[2], bnz1[3],
        whb, wzb);

    // layer 1 scan -> d_out
    hipMemsetAsync(bar, 0, 4096, stream);
    {
        const float* a0 = whb; const float* a1 = wzb;
        const float* a2 = uhW1; const float* a3 = uzW1;
        float* a4 = out0; unsigned* a5 = bar;
        void* args[] = {&a0, &a1, &a2, &a3, &a4, &a5};
        hipLaunchCooperativeKernel((const void*)scan_kernel, dim3(256), dim3(256), args, 0, stream);
    }

    // x_len pass-through as float values
    lencopy_kernel<<<1, 64, 0, stream>>>(xlen, out0 + NFLT);
}

// Round 4
// 37477.393 us; speedup vs baseline: 2.0813x; 1.1259x over previous
//
#include <hip/hip_runtime.h>
#include <math.h>

#define TT 1500
#define BB 16
#define HH 1024
#define MM (TT*BB)            // 24000
#define KEEPF 0.8f
#define EPSF 1e-5f
#define NFLT ((size_t)MM * HH)   // 24,576,000 floats per [T,B,H] buffer

#define AGENT __HIP_MEMORY_SCOPE_AGENT
typedef unsigned long long u64;

// ---------------- GEMM + folded BatchNorm (unchanged) ----------------
__global__ __launch_bounds__(256) void gemm_bn_kernel(
    const float* __restrict__ A, int K,
    const float* __restrict__ Wh, const float* __restrict__ Wz,
    const float* __restrict__ bnh_g, const float* __restrict__ bnh_b,
    const float* __restrict__ bnh_m, const float* __restrict__ bnh_v,
    const float* __restrict__ bnz_g, const float* __restrict__ bnz_b,
    const float* __restrict__ bnz_m, const float* __restrict__ bnz_v,
    float* __restrict__ outh, float* __restrict__ outz)
{
    __shared__ float As[16][68];
    __shared__ float Ws[16][68];
    const int mb = blockIdx.x;
    const int nb = blockIdx.y;
    const int jbase = nb * 64;
    const bool isz = jbase >= 1024;
    const float* W = isz ? Wz : Wh;
    const int jloc = isz ? (jbase - 1024) : jbase;

    const int tid = threadIdx.x;
    const int r = tid >> 2, q = tid & 3;
    const int tm = tid & 15, tn = tid >> 4;

    float acc[4][4] = {};
    for (int kt = 0; kt < K; kt += 16) {
        float4 a = *(const float4*)(A + (size_t)(mb * 64 + r) * K + kt + q * 4);
        float4 w = *(const float4*)(W + (size_t)(jloc + r) * K + kt + q * 4);
        __syncthreads();
        As[q*4+0][r] = a.x; As[q*4+1][r] = a.y; As[q*4+2][r] = a.z; As[q*4+3][r] = a.w;
        Ws[q*4+0][r] = w.x; Ws[q*4+1][r] = w.y; Ws[q*4+2][r] = w.z; Ws[q*4+3][r] = w.w;
        __syncthreads();
        #pragma unroll
        for (int k = 0; k < 16; ++k) {
            float4 a4 = *(const float4*)(&As[k][tm * 4]);
            float4 w4 = *(const float4*)(&Ws[k][tn * 4]);
            float av[4] = {a4.x, a4.y, a4.z, a4.w};
            float wv[4] = {w4.x, w4.y, w4.z, w4.w};
            #pragma unroll
            for (int i = 0; i < 4; ++i)
                #pragma unroll
                for (int j = 0; j < 4; ++j)
                    acc[i][j] += av[i] * wv[j];
        }
    }

    const float* g = isz ? bnz_g : bnh_g;
    const float* b = isz ? bnz_b : bnh_b;
    const float* m = isz ? bnz_m : bnh_m;
    const float* v = isz ? bnz_v : bnh_v;
    float* outp = isz ? outz : outh;

    float sc[4], sh[4];
    #pragma unroll
    for (int j = 0; j < 4; ++j) {
        int jc = jloc + tn * 4 + j;
        float s = g[jc] * rsqrtf(v[jc] + EPSF);
        sc[j] = s;
        sh[j] = b[jc] - m[jc] * s;
    }
    #pragma unroll
    for (int i = 0; i < 4; ++i) {
        int mrow = mb * 64 + tm * 4 + i;
        float4 o;
        o.x = acc[i][0] * sc[0] + sh[0];
        o.y = acc[i][1] * sc[1] + sh[1];
        o.z = acc[i][2] * sc[2] + sh[2];
        o.w = acc[i][3] * sc[3] + sh[3];
        *(float4*)(outp + (size_t)mrow * HH + jloc + tn * 4) = o;
    }
}

// ---------------- barrier-free flagged-chunk liGRU scan ----------------
// 256 blocks x 256 threads. Block owns columns [bid*4, bid*4+4) (both mats).
// lane bits: [4:0]=ks (k-slice), [5]=mat; wave id rg = rows [4rg, 4rg+4).
// Thread: 4 cols x 4 rows x 32 k (k = 4*ks + 128*it, it=0..7).
// U slice lives in VGPRs. h transported via coherent (L3) 8B atomics.
// Sync: 8 monotonic chunk counters (chunk g = blocks 32g..32g+31), each
// incremented once per block per step; h[t-1] ready when all reach 32*t.
// WATCHDOG: bounded spin (~0.5s) -> clean exit instead of GPU hang.
__global__ __launch_bounds__(256, 1) void scan_kernel(
    const float* __restrict__ wh, const float* __restrict__ wz,
    const float* __restrict__ uh, const float* __restrict__ uz,
    float* __restrict__ hout, unsigned* __restrict__ cnt)
{
    const int tid  = threadIdx.x, bid = blockIdx.x;
    const int lane = tid & 63;
    const int ks   = lane & 31;
    const int mat  = lane >> 5;
    const int rg   = tid >> 6;          // wave index: rows 4rg..4rg+3
    const int j0   = bid * 4;
    const int row0 = rg * 4;

    // ---- preload U slice into registers: u[c][it] = U[j0+c][4ks+128it ..+3]
    const float* Um = mat ? uz : uh;
    float4 u[4][8];
    #pragma unroll
    for (int c = 0; c < 4; ++c) {
        const float* up = Um + (size_t)(j0 + c) * HH + 4 * ks;
        #pragma unroll
        for (int it = 0; it < 8; ++it)
            u[c][it] = *(const float4*)(up + 128 * it);
    }

    const bool g0 = (lane == 0);        // one gate lane per wave
    float hprev[4][4];
    #pragma unroll
    for (int r = 0; r < 4; ++r)
        #pragma unroll
        for (int c = 0; c < 4; ++c) hprev[r][c] = 0.f;

    unsigned want = 0;                  // counters reach 32*t after step t-1 flags
    for (int t = 0; t < TT; ++t) {
        // prefetch gate inputs early (hidden under the h stream)
        float4 whv[4], wzv[4];
        if (g0) {
            #pragma unroll
            for (int r = 0; r < 4; ++r) {
                const size_t base = ((size_t)t * BB + row0 + r) * HH + j0;
                whv[r] = *(const float4*)(wh + base);
                wzv[r] = *(const float4*)(wz + base);
            }
        }

        float acc[4][4] = {};   // [c][r]
        if (t > 0) {
            // poll all 8 chunk counters for h[t-1] readiness (wave-coalesced);
            // bounded spin: on pathological stall, bail out (wrong answer,
            // GPU survives) instead of hanging the driver.
            int spins = 0;
            bool dead = false;
            while (!__all(__hip_atomic_load(cnt + ((lane & 7) << 5),
                                            __ATOMIC_RELAXED, AGENT) >= want)) {
                if (++spins > 4000000) { dead = true; break; }
                __builtin_amdgcn_s_sleep(2);
            }
            if (dead) break;                 // all waves of all blocks will trip too
            asm volatile("" ::: "memory");   // keep h loads below the poll

            const float* hb = hout + (size_t)(t - 1) * BB * HH;
            #pragma unroll
            for (int it = 0; it < 8; ++it) {
                #pragma unroll
                for (int r = 0; r < 4; ++r) {
                    const u64* p = (const u64*)(hb + (size_t)(row0 + r) * HH + 4 * ks + 128 * it);
                    u64 lo = __hip_atomic_load(p,     __ATOMIC_RELAXED, AGENT);
                    u64 hi = __hip_atomic_load(p + 1, __ATOMIC_RELAXED, AGENT);
                    const float f0 = __uint_as_float((unsigned)lo);
                    const float f1 = __uint_as_float((unsigned)(lo >> 32));
                    const float f2 = __uint_as_float((unsigned)hi);
                    const float f3 = __uint_as_float((unsigned)(hi >> 32));
                    #pragma unroll
                    for (int c = 0; c < 4; ++c)
                        acc[c][r] += f0 * u[c][it].x + f1 * u[c][it].y
                                   + f2 * u[c][it].z + f3 * u[c][it].w;
                }
            }
            // butterfly reduce over the 32 k-slices
            #pragma unroll
            for (int d = 1; d < 32; d <<= 1)
                #pragma unroll
                for (int c = 0; c < 4; ++c)
                    #pragma unroll
                    for (int r = 0; r < 4; ++r)
                        acc[c][r] += __shfl_xor(acc[c][r], d, 64);
        }
        // pair with the z-matrix partner (lane ^ 32 flips mat)
        float zacc[4][4];
        #pragma unroll
        for (int c = 0; c < 4; ++c)
            #pragma unroll
            for (int r = 0; r < 4; ++r)
                zacc[c][r] = __shfl_xor(acc[c][r], 32, 64);

        if (g0) {
            #pragma unroll
            for (int r = 0; r < 4; ++r) {
                float hn[4];
                #pragma unroll
                for (int c = 0; c < 4; ++c) {
                    const float zt = 1.f / (1.f + __expf(-((&wzv[r].x)[c] + zacc[c][r])));
                    const float at = (&whv[r].x)[c] + acc[c][r];
                    const float hc = fmaxf(at, 0.f) * KEEPF;
                    hn[c] = zt * hprev[r][c] + (1.f - zt) * hc;
                    hprev[r][c] = hn[c];
                }
                u64* dst = (u64*)(hout + ((size_t)t * BB + row0 + r) * HH + j0);
                union { float f[2]; u64 v; } p0, p1;
                p0.f[0] = hn[0]; p0.f[1] = hn[1];
                p1.f[0] = hn[2]; p1.f[1] = hn[3];
                __hip_atomic_store(dst,     p0.v, __ATOMIC_RELAXED, AGENT);
                __hip_atomic_store(dst + 1, p1.v, __ATOMIC_RELAXED, AGENT);
            }
        }
        __syncthreads();   // drains vmcnt for all waves -> block's stores are at L3
        if (tid == 0)
            __hip_atomic_fetch_add(cnt + ((bid >> 5) << 5), 1u, __ATOMIC_RELAXED, AGENT);
        want += 32;
    }
}

__global__ void lencopy_kernel(const int* __restrict__ xl, float* __restrict__ out) {
    int i = threadIdx.x;
    if (i < BB) out[i] = (float)xl[i];
}

extern "C" void kernel_launch(void* const* d_in, const int* in_sizes, int n_in,
                              void* d_out, int out_size, void* d_ws, size_t ws_size,
                              hipStream_t stream) {
    const float* x    = (const float*)d_in[0];
    const int*   xlen = (const int*)d_in[1];
    const float* whW0 = (const float*)d_in[2];
    const float* wzW0 = (const float*)d_in[3];
    const float* uhW0 = (const float*)d_in[4];
    const float* uzW0 = (const float*)d_in[5];
    const float* bnh0[4] = {(const float*)d_in[6], (const float*)d_in[7], (const float*)d_in[8], (const float*)d_in[9]};
    const float* bnz0[4] = {(const float*)d_in[10], (const float*)d_in[11], (const float*)d_in[12], (const float*)d_in[13]};
    const float* whW1 = (const float*)d_in[14];
    const float* wzW1 = (const float*)d_in[15];
    const float* uhW1 = (const float*)d_in[16];
    const float* uzW1 = (const float*)d_in[17];
    const float* bnh1[4] = {(const float*)d_in[18], (const float*)d_in[19], (const float*)d_in[20], (const float*)d_in[21]};
    const float* bnz1[4] = {(const float*)d_in[22], (const float*)d_in[23], (const float*)d_in[24], (const float*)d_in[25]};

    float* whb = (float*)d_ws;               // [M,H]
    float* wzb = whb + NFLT;                 // [M,H]
    float* h0  = wzb + NFLT;                 // [M,H]
    unsigned* bar = (unsigned*)((char*)d_ws + 3 * NFLT * sizeof(float));
    float* out0 = (float*)d_out;             // h1 [T,B,H]

    // zero both scans' counter sets (ws is re-poisoned before every launch)
    hipMemsetAsync(bar, 0, 4096, stream);

    dim3 ggrid(MM / 64, 32), gblk(256);

    // layer 0 projections + BN
    gemm_bn_kernel<<<ggrid, gblk, 0, stream>>>(
        x, 512, whW0, wzW0,
        bnh0[0], bnh0[1], bnh0[2], bnh0[3],
        bnz0[0], bnz0[1], bnz0[2], bnz0[3],
        whb, wzb);

    // layer 0 scan (counters at bar)
    {
        const float* a0 = whb; const float* a1 = wzb;
        const float* a2 = uhW0; const float* a3 = uzW0;
        float* a4 = h0; unsigned* a5 = bar;
        void* args[] = {&a0, &a1, &a2, &a3, &a4, &a5};
        hipLaunchCooperativeKernel((const void*)scan_kernel, dim3(256), dim3(256), args, 0, stream);
    }

    // layer 1 projections + BN (reuse wh/wz buffers)
    gemm_bn_kernel<<<ggrid, gblk, 0, stream>>>(
        h0, 1024, whW1, wzW1,
        bnh1[0], bnh1[1], bnh1[2], bnh1[3],
        bnz1[0], bnz1[1], bnz1[2], bnz1[3],
        whb, wzb);

    // layer 1 scan -> d_out (counters at bar+256, i.e. byte offset 1024)
    {
        const float* a0 = whb; const float* a1 = wzb;
        const float* a2 = uhW1; const float* a3 = uzW1;
        float* a4 = out0; unsigned* a5 = bar + 256;
        void* args[] = {&a0, &a1, &a2, &a3, &a4, &a5};
        hipLaunchCooperativeKernel((const void*)scan_kernel, dim3(256), dim3(256), args, 0, stream);
    }

    // x_len pass-through as float values
    lencopy_kernel<<<1, 64, 0, stream>>>(xlen, out0 + NFLT);
}

// Round 5
// 36582.474 us; speedup vs baseline: 2.1322x; 1.0245x over previous
//
#include <hip/hip_runtime.h>
#include <math.h>

#define TT 1500
#define BB 16
#define HH 1024
#define MM (TT*BB)            // 24000
#define KEEPF 0.8f
#define EPSF 1e-5f
#define NFLT ((size_t)MM * HH)   // 24,576,000 floats per [T,B,H] buffer

#define AGENT __HIP_MEMORY_SCOPE_AGENT
typedef unsigned long long u64;

// ---------------- GEMM + folded BatchNorm (unchanged) ----------------
__global__ __launch_bounds__(256) void gemm_bn_kernel(
    const float* __restrict__ A, int K,
    const float* __restrict__ Wh, const float* __restrict__ Wz,
    const float* __restrict__ bnh_g, const float* __restrict__ bnh_b,
    const float* __restrict__ bnh_m, const float* __restrict__ bnh_v,
    const float* __restrict__ bnz_g, const float* __restrict__ bnz_b,
    const float* __restrict__ bnz_m, const float* __restrict__ bnz_v,
    float* __restrict__ outh, float* __restrict__ outz)
{
    __shared__ float As[16][68];
    __shared__ float Ws[16][68];
    const int mb = blockIdx.x;
    const int nb = blockIdx.y;
    const int jbase = nb * 64;
    const bool isz = jbase >= 1024;
    const float* W = isz ? Wz : Wh;
    const int jloc = isz ? (jbase - 1024) : jbase;

    const int tid = threadIdx.x;
    const int r = tid >> 2, q = tid & 3;
    const int tm = tid & 15, tn = tid >> 4;

    float acc[4][4] = {};
    for (int kt = 0; kt < K; kt += 16) {
        float4 a = *(const float4*)(A + (size_t)(mb * 64 + r) * K + kt + q * 4);
        float4 w = *(const float4*)(W + (size_t)(jloc + r) * K + kt + q * 4);
        __syncthreads();
        As[q*4+0][r] = a.x; As[q*4+1][r] = a.y; As[q*4+2][r] = a.z; As[q*4+3][r] = a.w;
        Ws[q*4+0][r] = w.x; Ws[q*4+1][r] = w.y; Ws[q*4+2][r] = w.z; Ws[q*4+3][r] = w.w;
        __syncthreads();
        #pragma unroll
        for (int k = 0; k < 16; ++k) {
            float4 a4 = *(const float4*)(&As[k][tm * 4]);
            float4 w4 = *(const float4*)(&Ws[k][tn * 4]);
            float av[4] = {a4.x, a4.y, a4.z, a4.w};
            float wv[4] = {w4.x, w4.y, w4.z, w4.w};
            #pragma unroll
            for (int i = 0; i < 4; ++i)
                #pragma unroll
                for (int j = 0; j < 4; ++j)
                    acc[i][j] += av[i] * wv[j];
        }
    }

    const float* g = isz ? bnz_g : bnh_g;
    const float* b = isz ? bnz_b : bnh_b;
    const float* m = isz ? bnz_m : bnh_m;
    const float* v = isz ? bnz_v : bnh_v;
    float* outp = isz ? outz : outh;

    float sc[4], sh[4];
    #pragma unroll
    for (int j = 0; j < 4; ++j) {
        int jc = jloc + tn * 4 + j;
        float s = g[jc] * rsqrtf(v[jc] + EPSF);
        sc[j] = s;
        sh[j] = b[jc] - m[jc] * s;
    }
    #pragma unroll
    for (int i = 0; i < 4; ++i) {
        int mrow = mb * 64 + tm * 4 + i;
        float4 o;
        o.x = acc[i][0] * sc[0] + sh[0];
        o.y = acc[i][1] * sc[1] + sh[1];
        o.z = acc[i][2] * sc[2] + sh[2];
        o.w = acc[i][3] * sc[3] + sh[3];
        *(float4*)(outp + (size_t)mrow * HH + jloc + tn * 4) = o;
    }
}

// ---------------- barrier-free flagged-chunk liGRU scan ----------------
// 256 blocks x 256 threads. Block owns columns [bid*4, bid*4+4) (both mats).
// lane bits: [4:0]=ks (k-slice), [5]=mat; wave id rg = rows [4rg, 4rg+4).
// Thread: 4 cols x 4 rows x 32 k (k = 4*ks + 128*it, it=0..7).
// U slice lives in VGPRs.
// PRODUCE: coherent (sc-bit, L2-bypassing) 8B atomic stores push h[t] to L3,
//          __syncthreads drains vmcnt, one relaxed fetch_add per block flags.
// CONSUME: relaxed poll of 8 chunk counters, then PLAIN CACHED float4 loads.
//          Safe because h[t-1] lines are fresh addresses (never cached before;
//          kernel launch invalidated caches), so a miss fills from L3 with the
//          pushed data, and blocks sharing an XCD reuse each other's L2 fills.
// WATCHDOG: bounded spin (~0.5s) -> clean exit instead of GPU hang.
__global__ __launch_bounds__(256, 1) void scan_kernel(
    const float* __restrict__ wh, const float* __restrict__ wz,
    const float* __restrict__ uh, const float* __restrict__ uz,
    float* __restrict__ hout, unsigned* __restrict__ cnt)
{
    const int tid  = threadIdx.x, bid = blockIdx.x;
    const int lane = tid & 63;
    const int ks   = lane & 31;
    const int mat  = lane >> 5;
    const int rg   = tid >> 6;          // wave index: rows 4rg..4rg+3
    const int j0   = bid * 4;
    const int row0 = rg * 4;

    // ---- preload U slice into registers: u[c][it] = U[j0+c][4ks+128it ..+3]
    const float* Um = mat ? uz : uh;
    float4 u[4][8];
    #pragma unroll
    for (int c = 0; c < 4; ++c) {
        const float* up = Um + (size_t)(j0 + c) * HH + 4 * ks;
        #pragma unroll
        for (int it = 0; it < 8; ++it)
            u[c][it] = *(const float4*)(up + 128 * it);
    }

    const bool g0 = (lane == 0);        // one gate lane per wave
    float hprev[4][4];
    #pragma unroll
    for (int r = 0; r < 4; ++r)
        #pragma unroll
        for (int c = 0; c < 4; ++c) hprev[r][c] = 0.f;

    unsigned want = 0;                  // counters reach 32*t after step t-1 flags
    for (int t = 0; t < TT; ++t) {
        // prefetch gate inputs early (hidden under the h stream)
        float4 whv[4], wzv[4];
        if (g0) {
            #pragma unroll
            for (int r = 0; r < 4; ++r) {
                const size_t base = ((size_t)t * BB + row0 + r) * HH + j0;
                whv[r] = *(const float4*)(wh + base);
                wzv[r] = *(const float4*)(wz + base);
            }
        }

        float acc[4][4] = {};   // [c][r]
        if (t > 0) {
            // poll all 8 chunk counters for h[t-1] readiness (wave-coalesced);
            // bounded spin: on pathological stall, bail out (wrong answer,
            // GPU survives) instead of hanging the driver.
            int spins = 0;
            bool dead = false;
            while (!__all(__hip_atomic_load(cnt + ((lane & 7) << 5),
                                            __ATOMIC_RELAXED, AGENT) >= want)) {
                if (++spins > 4000000) { dead = true; break; }
                __builtin_amdgcn_s_sleep(2);
            }
            if (dead) break;                 // all waves of all blocks will trip too
            asm volatile("" ::: "memory");   // keep h loads below the poll

            // plain cached vector loads: pipelined by the compiler, L2-shared
            // across the XCD's 32 blocks.
            const float* hb = hout + (size_t)(t - 1) * BB * HH;
            #pragma unroll
            for (int it = 0; it < 8; ++it) {
                #pragma unroll
                for (int r = 0; r < 4; ++r) {
                    const float4 hv = *(const float4*)(hb + (size_t)(row0 + r) * HH + 4 * ks + 128 * it);
                    #pragma unroll
                    for (int c = 0; c < 4; ++c)
                        acc[c][r] += hv.x * u[c][it].x + hv.y * u[c][it].y
                                   + hv.z * u[c][it].z + hv.w * u[c][it].w;
                }
            }
            // butterfly reduce over the 32 k-slices
            #pragma unroll
            for (int d = 1; d < 32; d <<= 1)
                #pragma unroll
                for (int c = 0; c < 4; ++c)
                    #pragma unroll
                    for (int r = 0; r < 4; ++r)
                        acc[c][r] += __shfl_xor(acc[c][r], d, 64);
        }
        // pair with the z-matrix partner (lane ^ 32 flips mat)
        float zacc[4][4];
        #pragma unroll
        for (int c = 0; c < 4; ++c)
            #pragma unroll
            for (int r = 0; r < 4; ++r)
                zacc[c][r] = __shfl_xor(acc[c][r], 32, 64);

        if (g0) {
            #pragma unroll
            for (int r = 0; r < 4; ++r) {
                float hn[4];
                #pragma unroll
                for (int c = 0; c < 4; ++c) {
                    const float zt = 1.f / (1.f + __expf(-((&wzv[r].x)[c] + zacc[c][r])));
                    const float at = (&whv[r].x)[c] + acc[c][r];
                    const float hc = fmaxf(at, 0.f) * KEEPF;
                    hn[c] = zt * hprev[r][c] + (1.f - zt) * hc;
                    hprev[r][c] = hn[c];
                }
                u64* dst = (u64*)(hout + ((size_t)t * BB + row0 + r) * HH + j0);
                union { float f[2]; u64 v; } p0, p1;
                p0.f[0] = hn[0]; p0.f[1] = hn[1];
                p1.f[0] = hn[2]; p1.f[1] = hn[3];
                __hip_atomic_store(dst,     p0.v, __ATOMIC_RELAXED, AGENT);
                __hip_atomic_store(dst + 1, p1.v, __ATOMIC_RELAXED, AGENT);
            }
        }
        __syncthreads();   // drains vmcnt for all waves -> block's stores are at L3
        if (tid == 0)
            __hip_atomic_fetch_add(cnt + ((bid >> 5) << 5), 1u, __ATOMIC_RELAXED, AGENT);
        want += 32;
    }
}

__global__ void lencopy_kernel(const int* __restrict__ xl, float* __restrict__ out) {
    int i = threadIdx.x;
    if (i < BB) out[i] = (float)xl[i];
}

extern "C" void kernel_launch(void* const* d_in, const int* in_sizes, int n_in,
                              void* d_out, int out_size, void* d_ws, size_t ws_size,
                              hipStream_t stream) {
    const float* x    = (const float*)d_in[0];
    const int*   xlen = (const int*)d_in[1];
    const float* whW0 = (const float*)d_in[2];
    const float* wzW0 = (const float*)d_in[3];
    const float* uhW0 = (const float*)d_in[4];
    const float* uzW0 = (const float*)d_in[5];
    const float* bnh0[4] = {(const float*)d_in[6], (const float*)d_in[7], (const float*)d_in[8], (const float*)d_in[9]};
    const float* bnz0[4] = {(const float*)d_in[10], (const float*)d_in[11], (const float*)d_in[12], (const float*)d_in[13]};
    const float* whW1 = (const float*)d_in[14];
    const float* wzW1 = (const float*)d_in[15];
    const float* uhW1 = (const float*)d_in[16];
    const float* uzW1 = (const float*)d_in[17];
    const float* bnh1[4] = {(const float*)d_in[18], (const float*)d_in[19], (const float*)d_in[20], (const float*)d_in[21]};
    const float* bnz1[4] = {(const float*)d_in[22], (const float*)d_in[23], (const float*)d_in[24], (const float*)d_in[25]};

    float* whb = (float*)d_ws;               // [M,H]
    float* wzb = whb + NFLT;                 // [M,H]
    float* h0  = wzb + NFLT;                 // [M,H]
    unsigned* bar = (unsigned*)((char*)d_ws + 3 * NFLT * sizeof(float));
    float* out0 = (float*)d_out;             // h1 [T,B,H]

    // zero both scans' counter sets (ws is re-poisoned before every launch)
    hipMemsetAsync(bar, 0, 4096, stream);

    dim3 ggrid(MM / 64, 32), gblk(256);

    // layer 0 projections + BN
    gemm_bn_kernel<<<ggrid, gblk, 0, stream>>>(
        x, 512, whW0, wzW0,
        bnh0[0], bnh0[1], bnh0[2], bnh0[3],
        bnz0[0], bnz0[1], bnz0[2], bnz0[3],
        whb, wzb);

    // layer 0 scan (counters at bar)
    {
        const float* a0 = whb; const float* a1 = wzb;
        const float* a2 = uhW0; const float* a3 = uzW0;
        float* a4 = h0; unsigned* a5 = bar;
        void* args[] = {&a0, &a1, &a2, &a3, &a4, &a5};
        hipLaunchCooperativeKernel((const void*)scan_kernel, dim3(256), dim3(256), args, 0, stream);
    }

    // layer 1 projections + BN (reuse wh/wz buffers)
    gemm_bn_kernel<<<ggrid, gblk, 0, stream>>>(
        h0, 1024, whW1, wzW1,
        bnh1[0], bnh1[1], bnh1[2], bnh1[3],
        bnz1[0], bnz1[1], bnz1[2], bnz1[3],
        whb, wzb);

    // layer 1 scan -> d_out (counters at bar+256, i.e. byte offset 1024)
    {
        const float* a0 = whb; const float* a1 = wzb;
        const float* a2 = uhW1; const float* a3 = uzW1;
        float* a4 = out0; unsigned* a5 = bar + 256;
        void* args[] = {&a0, &a1, &a2, &a3, &a4, &a5};
        hipLaunchCooperativeKernel((const void*)scan_kernel, dim3(256), dim3(256), args, 0, stream);
    }

    // x_len pass-through as float values
    lencopy_kernel<<<1, 64, 0, stream>>>(xlen, out0 + NFLT);
}

// Round 7
// 32944.580 us; speedup vs baseline: 2.3677x; 1.1104x over previous
//
#include <hip/hip_runtime.h>
#include <math.h>

#define TT 1500
#define BB 16
#define HH 1024
#define MM (TT*BB)            // 24000
#define KEEPF 0.8f
#define EPSF 1e-5f
#define NFLT ((size_t)MM * HH)   // 24,576,000 floats per [T,B,H] buffer

#define AGENT __HIP_MEMORY_SCOPE_AGENT
typedef unsigned long long u64;

// ---------------- GEMM + folded BatchNorm (unchanged) ----------------
__global__ __launch_bounds__(256) void gemm_bn_kernel(
    const float* __restrict__ A, int K,
    const float* __restrict__ Wh, const float* __restrict__ Wz,
    const float* __restrict__ bnh_g, const float* __restrict__ bnh_b,
    const float* __restrict__ bnh_m, const float* __restrict__ bnh_v,
    const float* __restrict__ bnz_g, const float* __restrict__ bnz_b,
    const float* __restrict__ bnz_m, const float* __restrict__ bnz_v,
    float* __restrict__ outh, float* __restrict__ outz)
{
    __shared__ float As[16][68];
    __shared__ float Ws[16][68];
    const int mb = blockIdx.x;
    const int nb = blockIdx.y;
    const int jbase = nb * 64;
    const bool isz = jbase >= 1024;
    const float* W = isz ? Wz : Wh;
    const int jloc = isz ? (jbase - 1024) : jbase;

    const int tid = threadIdx.x;
    const int r = tid >> 2, q = tid & 3;
    const int tm = tid & 15, tn = tid >> 4;

    float acc[4][4] = {};
    for (int kt = 0; kt < K; kt += 16) {
        float4 a = *(const float4*)(A + (size_t)(mb * 64 + r) * K + kt + q * 4);
        float4 w = *(const float4*)(W + (size_t)(jloc + r) * K + kt + q * 4);
        __syncthreads();
        As[q*4+0][r] = a.x; As[q*4+1][r] = a.y; As[q*4+2][r] = a.z; As[q*4+3][r] = a.w;
        Ws[q*4+0][r] = w.x; Ws[q*4+1][r] = w.y; Ws[q*4+2][r] = w.z; Ws[q*4+3][r] = w.w;
        __syncthreads();
        #pragma unroll
        for (int k = 0; k < 16; ++k) {
            float4 a4 = *(const float4*)(&As[k][tm * 4]);
            float4 w4 = *(const float4*)(&Ws[k][tn * 4]);
            float av[4] = {a4.x, a4.y, a4.z, a4.w};
            float wv[4] = {w4.x, w4.y, w4.z, w4.w};
            #pragma unroll
            for (int i = 0; i < 4; ++i)
                #pragma unroll
                for (int j = 0; j < 4; ++j)
                    acc[i][j] += av[i] * wv[j];
        }
    }

    const float* g = isz ? bnz_g : bnh_g;
    const float* b = isz ? bnz_b : bnh_b;
    const float* m = isz ? bnz_m : bnh_m;
    const float* v = isz ? bnz_v : bnh_v;
    float* outp = isz ? outz : outh;

    float sc[4], sh[4];
    #pragma unroll
    for (int j = 0; j < 4; ++j) {
        int jc = jloc + tn * 4 + j;
        float s = g[jc] * rsqrtf(v[jc] + EPSF);
        sc[j] = s;
        sh[j] = b[jc] - m[jc] * s;
    }
    #pragma unroll
    for (int i = 0; i < 4; ++i) {
        int mrow = mb * 64 + tm * 4 + i;
        float4 o;
        o.x = acc[i][0] * sc[0] + sh[0];
        o.y = acc[i][1] * sc[1] + sh[1];
        o.z = acc[i][2] * sc[2] + sh[2];
        o.w = acc[i][3] * sc[3] + sh[3];
        *(float4*)(outp + (size_t)mrow * HH + jloc + tn * 4) = o;
    }
}

// ---------------- batch-partitioned liGRU scan, per-block counters ----------------
// 256 blocks = 4 groups x 64; group g owns batch rows [4g,4g+4) (independent
// recurrences). Block owns 16 CONTIGUOUS columns [16*ib,16*ib+16) -> every
// 64B wh/wz/h line belongs to exactly one block (no over-fetch, no write
// amplification). Wave wv: cols [c0,c0+4), lane bit5 = mat, ks = lane&31.
// PRODUCE: gate lane stores 4x4 h-slice (coherent sc-bit 8B stores),
//          s_waitcnt vmcnt(0) (wave-local ack), then ONE fire-and-forget
//          fetch_add on the block's PRIVATE 16B counter line (4 adds/block/
//          step, distinct lines -> no contention). NO barrier in the loop.
// CONSUME: lane L polls counter of block (g*64+L) for >= 4t (1 atomic load
//          per lane per round, 64 distinct lines, s_sleep backoff), then
//          plain cached float4 h loads (fresh addresses; L2-shared per XCD).
// WATCHDOG: bounded spin -> clean per-wave exit (no barrier -> no strand).
__global__ __launch_bounds__(256, 1) void scan_kernel(
    const float* __restrict__ wh, const float* __restrict__ wz,
    const float* __restrict__ uh, const float* __restrict__ uz,
    float* __restrict__ hout, unsigned* __restrict__ cnt)
{
    const int tid  = threadIdx.x, bid = blockIdx.x;
    const int lane = tid & 63;
    const int wv   = tid >> 6;          // wave 0..3
    const int ks   = lane & 31;
    const int mat  = lane >> 5;
    const int g    = bid >> 6;          // batch group: rows 4g..4g+3
    const int ib   = bid & 63;          // block-in-group: cols 16ib..16ib+15
    const int c0   = ib * 16 + wv * 4;  // this wave's 4 columns
    const int row0 = g * 4;

    // ---- preload U slice into registers: u[c][it] = U[c0+c][4ks+128it ..+3]
    const float* Um = mat ? uz : uh;
    float4 u[4][8];
    #pragma unroll
    for (int c = 0; c < 4; ++c) {
        const float* up = Um + (size_t)(c0 + c) * HH + 4 * ks;
        #pragma unroll
        for (int it = 0; it < 8; ++it)
            u[c][it] = *(const float4*)(up + 128 * it);
    }

    const bool g0 = (lane == 0);        // gate lane of this wave
    float hprev[4][4];                  // [r][c]
    #pragma unroll
    for (int r = 0; r < 4; ++r)
        #pragma unroll
        for (int c = 0; c < 4; ++c) hprev[r][c] = 0.f;

    unsigned* mycnt = cnt + ((unsigned)bid << 2);           // private 16B line
    const unsigned* gcnt = cnt + ((unsigned)(g * 64) << 2); // group's 64 lines

    for (int t = 0; t < TT; ++t) {
        // prefetch gate inputs early (hidden under poll + dot)
        float4 whv[4], wzv[4];
        if (g0) {
            #pragma unroll
            for (int r = 0; r < 4; ++r) {
                const size_t base = ((size_t)t * BB + row0 + r) * HH + c0;
                whv[r] = *(const float4*)(wh + base);
                wzv[r] = *(const float4*)(wz + base);
            }
        }

        float acc[4][4] = {};   // [c][r]
        if (t > 0) {
            // poll: lane L watches block (g*64+L); ready when all >= 4t
            const unsigned want = 4u * (unsigned)t;
            int spins = 0;
            bool dead = false;
            unsigned v = __hip_atomic_load(gcnt + (lane << 2), __ATOMIC_RELAXED, AGENT);
            while (!__all(v >= want)) {
                if (++spins > 4000000) { dead = true; break; }
                __builtin_amdgcn_s_sleep(4);
                v = __hip_atomic_load(gcnt + (lane << 2), __ATOMIC_RELAXED, AGENT);
            }
            if (dead) break;                 // no barriers -> clean unwind
            asm volatile("" ::: "memory");   // keep h loads below the poll

            // plain cached vector loads of the group's 4 rows of h[t-1]
            const float* hb = hout + (size_t)(t - 1) * BB * HH;
            #pragma unroll
            for (int it = 0; it < 8; ++it) {
                #pragma unroll
                for (int r = 0; r < 4; ++r) {
                    const float4 hv = *(const float4*)(hb + (size_t)(row0 + r) * HH + 4 * ks + 128 * it);
                    #pragma unroll
                    for (int c = 0; c < 4; ++c)
                        acc[c][r] += hv.x * u[c][it].x + hv.y * u[c][it].y
                                   + hv.z * u[c][it].z + hv.w * u[c][it].w;
                }
            }
            // butterfly reduce over the 32 k-slices
            #pragma unroll
            for (int d = 1; d < 32; d <<= 1)
                #pragma unroll
                for (int c = 0; c < 4; ++c)
                    #pragma unroll
                    for (int r = 0; r < 4; ++r)
                        acc[c][r] += __shfl_xor(acc[c][r], d, 64);
        }
        // pair with the z-matrix partner (lane ^ 32 flips mat)
        float zacc[4][4];
        #pragma unroll
        for (int c = 0; c < 4; ++c)
            #pragma unroll
            for (int r = 0; r < 4; ++r)
                zacc[c][r] = __shfl_xor(acc[c][r], 32, 64);

        if (g0) {
            #pragma unroll
            for (int r = 0; r < 4; ++r) {
                float hn[4];
                #pragma unroll
                for (int c = 0; c < 4; ++c) {
                    const float zt = 1.f / (1.f + __expf(-((&wzv[r].x)[c] + zacc[c][r])));
                    const float at = (&whv[r].x)[c] + acc[c][r];
                    const float hc = fmaxf(at, 0.f) * KEEPF;
                    hn[c] = zt * hprev[r][c] + (1.f - zt) * hc;
                    hprev[r][c] = hn[c];
                }
                u64* dst = (u64*)(hout + ((size_t)t * BB + row0 + r) * HH + c0);
                union { float f[2]; u64 v; } p0, p1;
                p0.f[0] = hn[0]; p0.f[1] = hn[1];
                p1.f[0] = hn[2]; p1.f[1] = hn[3];
                __hip_atomic_store(dst,     p0.v, __ATOMIC_RELAXED, AGENT);
                __hip_atomic_store(dst + 1, p1.v, __ATOMIC_RELAXED, AGENT);
            }
            // wait ONLY this wave's store acks, then bump the block counter
            asm volatile("s_waitcnt vmcnt(0)" ::: "memory");
            __hip_atomic_fetch_add(mycnt, 1u, __ATOMIC_RELAXED, AGENT);
        }
    }
}

__global__ void lencopy_kernel(const int* __restrict__ xl, float* __restrict__ out) {
    int i = threadIdx.x;
    if (i < BB) out[i] = (float)xl[i];
}

extern "C" void kernel_launch(void* const* d_in, const int* in_sizes, int n_in,
                              void* d_out, int out_size, void* d_ws, size_t ws_size,
                              hipStream_t stream) {
    const float* x    = (const float*)d_in[0];
    const int*   xlen = (const int*)d_in[1];
    const float* whW0 = (const float*)d_in[2];
    const float* wzW0 = (const float*)d_in[3];
    const float* uhW0 = (const float*)d_in[4];
    const float* uzW0 = (const float*)d_in[5];
    const float* bnh0[4] = {(const float*)d_in[6], (const float*)d_in[7], (const float*)d_in[8], (const float*)d_in[9]};
    const float* bnz0[4] = {(const float*)d_in[10], (const float*)d_in[11], (const float*)d_in[12], (const float*)d_in[13]};
    const float* whW1 = (const float*)d_in[14];
    const float* wzW1 = (const float*)d_in[15];
    const float* uhW1 = (const float*)d_in[16];
    const float* uzW1 = (const float*)d_in[17];
    const float* bnh1[4] = {(const float*)d_in[18], (const float*)d_in[19], (const float*)d_in[20], (const float*)d_in[21]};
    const float* bnz1[4] = {(const float*)d_in[22], (const float*)d_in[23], (const float*)d_in[24], (const float*)d_in[25]};

    float* whb = (float*)d_ws;               // [M,H]
    float* wzb = whb + NFLT;                 // [M,H]
    float* h0  = wzb + NFLT;                 // [M,H]
    unsigned* cnt0 = (unsigned*)((char*)d_ws + 3 * NFLT * sizeof(float));  // 4 KB
    unsigned* cnt1 = cnt0 + 1024;                                           // 4 KB
    float* out0 = (float*)d_out;             // h1 [T,B,H]

    // zero both scans' counters (ws is re-poisoned before every launch)
    hipMemsetAsync(cnt0, 0, 8192, stream);

    dim3 ggrid(MM / 64, 32), gblk(256);

    // layer 0 projections + BN
    gemm_bn_kernel<<<ggrid, gblk, 0, stream>>>(
        x, 512, whW0, wzW0,
        bnh0[0], bnh0[1], bnh0[2], bnh0[3],
        bnz0[0], bnz0[1], bnz0[2], bnz0[3],
        whb, wzb);

    // layer 0 scan
    {
        const float* a0 = whb; const float* a1 = wzb;
        const float* a2 = uhW0; const float* a3 = uzW0;
        float* a4 = h0; unsigned* a5 = cnt0;
        void* args[] = {&a0, &a1, &a2, &a3, &a4, &a5};
        hipLaunchCooperativeKernel((const void*)scan_kernel, dim3(256), dim3(256), args, 0, stream);
    }

    // layer 1 projections + BN (reuse wh/wz buffers)
    gemm_bn_kernel<<<ggrid, gblk, 0, stream>>>(
        h0, 1024, whW1, wzW1,
        bnh1[0], bnh1[1], bnh1[2], bnh1[3],
        bnz1[0], bnz1[1], bnz1[2], bnz1[3],
        whb, wzb);

    // layer 1 scan -> d_out
    {
        const float* a0 = whb; const float* a1 = wzb;
        const float* a2 = uhW1; const float* a3 = uzW1;
        float* a4 = out0; unsigned* a5 = cnt1;
        void* args[] = {&a0, &a1, &a2, &a3, &a4, &a5};
        hipLaunchCooperativeKernel((const void*)scan_kernel, dim3(256), dim3(256), args, 0, stream);
    }

    // x_len pass-through as float values
    lencopy_kernel<<<1, 64, 0, stream>>>(xlen, out0 + NFLT);
}